// Round 14
// baseline (128.958 us; speedup 1.0000x reference)
//
#include <hip/hip_runtime.h>
#include <hip/hip_bf16.h>

#define NB   4
#define CCH  256
#define CQK  32
#define NTOK 4096
#define LOG2E 1.4426950408889634f

typedef unsigned short u16;
typedef unsigned int   u32;
typedef __attribute__((ext_vector_type(8))) __bf16 bf16x8;
typedef __attribute__((ext_vector_type(4))) float  f32x4;
typedef __attribute__((ext_vector_type(4))) u32    u32x4;

union bfu { bf16x8 v; u16 s[8]; u32 w[4]; };

static __device__ __forceinline__ u16 f2bf(float f) {
  union { __hip_bfloat16 h; u16 u; } c; c.h = __float2bfloat16(f); return c.u;
}
static __device__ __forceinline__ float bf2f(u16 u) {
  union { __hip_bfloat16 h; u16 u; } c; c.u = u; return __bfloat162float(c.h);
}
// Safe packed f32->bf16 pair (round-half-up, ~ulp of RNE). Plain integer ops
// (R11's v_cvt_pk_bf16_f32 asm was the correctness poison — do not reuse).
static __device__ __forceinline__ u32 pkbf(float a, float b) {
  u32 ua = __builtin_bit_cast(u32, a) + 0x8000u;
  u32 ub = __builtin_bit_cast(u32, b) + 0x8000u;
  return (ua >> 16) | (ub & 0xFFFF0000u);
}
static __device__ __forceinline__ f32x4 mfma16(bf16x8 a, bf16x8 b, f32x4 c) {
  return __builtin_amdgcn_mfma_f32_16x16x32_bf16(a, b, c, 0, 0, 0);
}

// V tiled layout (since R9): per (b, ch=m/64) a CONTIGUOUS 32KB slab
// [ct 16][mh 2][512 u16]; u16 slot (hi*16+lo)*8+j =
// V[m=ch*64+mh*32+16*(j>>2)+4hi+(j&3)][c=ct*16+lo].
// Attn stages the whole slab to LDS with global_load_lds (linear copy).

// ---------------- Kernel 0: split W to bf16 hi/lo (once, tiny) ----------------
__global__ __launch_bounds__(256) void convert_w(
    const float* __restrict__ wq, const float* __restrict__ wk,
    const float* __restrict__ wv, u16* __restrict__ whi, u16* __restrict__ wlo)
{
  int i   = blockIdx.x * 256 + threadIdx.x;  // float4 index, 320*64 total
  int row = i >> 6;
  int col = (i & 63) * 4;
  const float* src = (row < 32) ? wq + row * CCH
                   : (row < 64) ? wk + (row - 32) * CCH
                                : wv + (row - 64) * CCH;
  float sc = (row < 32) ? LOG2E : 1.0f;
  float4 v = *(const float4*)(src + col);
  float f[4] = { v.x * sc, v.y * sc, v.z * sc, v.w * sc };
  u16 h[4], l[4];
#pragma unroll
  for (int j = 0; j < 4; j++) {
    h[j] = f2bf(f[j]);
    l[j] = f2bf(f[j] - bf2f(h[j]));
  }
  uint2 ph = { (u32)h[0] | ((u32)h[1] << 16), (u32)h[2] | ((u32)h[3] << 16) };
  uint2 pl = { (u32)l[0] | ((u32)l[1] << 16), (u32)l[2] | ((u32)l[3] << 16) };
  *(uint2*)(whi + (size_t)i * 4) = ph;
  *(uint2*)(wlo + (size_t)i * 4) = pl;
}

// ---------------- Kernel 1: MFMA QKV projection (n-tile 16, 4 blocks/CU) -----
__attribute__((amdgpu_waves_per_eu(4, 4)))
__global__ __launch_bounds__(256) void qkv_proj(
    const float* __restrict__ x,
    const float* __restrict__ bq, const float* __restrict__ bk,
    const float* __restrict__ bv,
    const u16* __restrict__ whi, const u16* __restrict__ wlo,
    u16* __restrict__ Qo, u16* __restrict__ Ko, u16* __restrict__ Vo)
{
  const int nt = blockIdx.x;   // 0..255
  const int b  = blockIdx.y;
  const int n0 = nt * 16;
  const int tid = threadIdx.x;
  const int w = tid >> 6, lane = tid & 63, lo = lane & 15, hi = lane >> 4;

  const f32x4 fz = { 0.f, 0.f, 0.f, 0.f };
  f32x4 acc[5];
#pragma unroll
  for (int t = 0; t < 5; t++) acc[t] = fz;

  const float* xb = x + (size_t)b * CCH * NTOK;

  for (int k = 0; k < 8; k++) {
    const int ck = k * 32;
    const float* xc = xb + (size_t)(ck + hi * 8) * NTOK + n0 + lo;
    u32  bw[8];
    float rl[8];
#pragma unroll
    for (int j = 0; j < 8; j++) {
      float f  = xc[(size_t)j * NTOK];
      u32 bits = __builtin_bit_cast(u32, f);
      float fh = __builtin_bit_cast(float, bits & 0xFFFF0000u);
      bw[j] = bits;
      rl[j] = f - fh;
    }
    bfu H, L;
#pragma unroll
    for (int j = 0; j < 4; j++) {
      H.w[j] = (bw[2 * j] >> 16) | (bw[2 * j + 1] & 0xFFFF0000u);
      L.w[j] = pkbf(rl[2 * j], rl[2 * j + 1]);
    }
    bf16x8 xh = H.v, xl = L.v;
#pragma unroll
    for (int t = 0; t < 5; t++) {
      const int ot = w + t * 4;
      const size_t woff = (size_t)(ot * 16 + lo) * CCH + ck + hi * 8;
      bf16x8 wh = *(const bf16x8*)(whi + woff);
      bf16x8 wl = *(const bf16x8*)(wlo + woff);
      if (t == 0) {   // Q/K: D[row=o][col=n]
        acc[t] = mfma16(wh, xh, acc[t]);
        acc[t] = mfma16(wh, xl, acc[t]);
        acc[t] = mfma16(wl, xh, acc[t]);
      } else {        // V: D[row=n][col=c]
        acc[t] = mfma16(xh, wh, acc[t]);
        acc[t] = mfma16(xl, wh, acc[t]);
        acc[t] = mfma16(xh, wl, acc[t]);
      }
    }
  }

  {
    const float* bsrc = (w < 2) ? bq : bk;
    const float  sc   = (w < 2) ? LOG2E : 1.0f;
    float4 b4 = *(const float4*)(bsrc + (w & 1) * 16 + hi * 4);
    float b0 = b4.x * sc, b1 = b4.y * sc, b2 = b4.z * sc, b3 = b4.w * sc;
    u16* base = (w < 2) ? Qo : Ko;
    int n = n0 + lo;
    f32x4 a = acc[0];
    uint2 pk = { pkbf(a[0] + b0, a[1] + b1), pkbf(a[2] + b2, a[3] + b3) };
    *(uint2*)(base + ((size_t)b * NTOK + n) * CQK + (w & 1) * 16 + hi * 4) = pk;
  }
  // V epilogue -> tiled layout (this block covers one 16-m sub-block).
  {
    const int chk  = n0 >> 6;
    const int mh   = (n0 >> 5) & 1;
    const int nt2g = (n0 >> 4) & 1;
    u16* vtb = Vo + ((size_t)b * 64 + chk) * 16384 + mh * 512
             + (hi * 16 + lo) * 8 + nt2g * 4;
#pragma unroll
    for (int t = 1; t < 5; t++) {
      int ct = w + t * 4 - 4;
      float bvc = bv[ct * 16 + lo];
      f32x4 a = acc[t];
      uint2 pk = { pkbf(a[0] + bvc, a[1] + bvc), pkbf(a[2] + bvc, a[3] + bvc) };
      *(uint2*)(vtb + (size_t)ct * 1024) = pk;
    }
  }
}

// ---------------- Kernel 2: flash attention, LDS-staged V ----------------
// R13 wave roles (qh, ch2, mh). V per chunk = one contiguous 32KB slab staged
// once per block via global_load_lds (L1 traffic halves vs per-wave V loads);
// waves ds_read_b128 their fragments. One barrier per chunk; vmcnt(0) placed
// where only the ~1-chunk-old stage is outstanding (robust, ~0 stall).
__attribute__((amdgpu_waves_per_eu(2, 2)))
__global__ __launch_bounds__(512) void attn(
    const float* __restrict__ x,
    const u16* __restrict__ Qm, const u16* __restrict__ Km,
    const u16* __restrict__ Vm, float* __restrict__ out)
{
  const int g   = blockIdx.x;
  const int lw3 = g & 7;
  const int b   = lw3 >> 1;                      // batch -> XCD pair
  const int qt6 = ((g >> 3) << 1) | (lw3 & 1);
  const int q0  = qt6 * 64;

  const int tid  = threadIdx.x;
  const int w    = tid >> 6;
  const int lane = tid & 63;
  const int lo   = lane & 15;
  const int hi   = lane >> 4;
  const int qh   = w >> 2;               // 0/1: q 32-half
  const int ch2  = (w >> 1) & 1;         // 0/1: c 128-half
  const int mh   = w & 1;                // 0/1: m 32-half
  const int qA   = q0 + qh * 32;
  const int qB   = qA + 16;
  const int ct0  = ch2 * 8;              // first of 8 c-tiles

  // smem: main loop = Vs[2][16384] u16 (2x32KB). Epilogue aliases it:
  // Ox f32x4[4][2][8][64] (64KB) @0, Lx f32x4[4][2][64] (8KB) @65536.
  __shared__ __align__(16) char smem[73728];
  u16* Vs = (u16*)smem;

  const f32x4 fz = { 0.f, 0.f, 0.f, 0.f };
  const u16* Kb    = Km + (size_t)b * NTOK * CQK;
  const u16* Vslab = Vm + (size_t)b * 64 * 16384;

  const bf16x8 qfA = *(const bf16x8*)(Qm + ((size_t)b * NTOK + qA + lo) * CQK + hi * 8);
  const bf16x8 qfB = *(const bf16x8*)(Qm + ((size_t)b * NTOK + qB + lo) * CQK + hi * 8);

  bfu onesu;
#pragma unroll
  for (int j = 0; j < 8; j++) onesu.s[j] = 0x3F80;
  const bf16x8 ones = onesu.v;

  f32x4 acc[2][8];
#pragma unroll
  for (int t = 0; t < 2; t++)
#pragma unroll
    for (int ct = 0; ct < 8; ct++) acc[t][ct] = fz;
  f32x4 acc_lA = fz, acc_lB = fz;

  bf16x8 vf[8];
  bf16x8 kfA[2], kfB[2];
  u32x4 pEA, pEB, pOA, pOB;

  // Stage V slab (chunk chk) -> LDS buffer buf_: 512 thr x 4 x 16B = 32KB.
#define STAGE(buf_, chk) do {                                                  \
    const u16* s_ = Vslab + (size_t)(chk) * 16384 + tid * 8;                   \
    u16* d_ = Vs + (buf_) * 16384 + tid * 8;                                   \
    _Pragma("unroll")                                                          \
    for (int r_ = 0; r_ < 4; r_++)                                             \
      __builtin_amdgcn_global_load_lds(                                        \
        (const __attribute__((address_space(1))) void*)(s_ + r_ * 4096),       \
        (__attribute__((address_space(3))) void*)(d_ + r_ * 4096), 16, 0, 0);  \
  } while (0)

#define RD_VF(buf_) do {                                                       \
    const u16* vb_ = Vs + (buf_) * 16384 + ct0 * 1024 + mh * 512 + lane * 8;   \
    _Pragma("unroll")                                                          \
    for (int ct_ = 0; ct_ < 8; ct_++)                                          \
      vf[ct_] = *(const bf16x8*)(vb_ + ct_ * 1024);                            \
  } while (0)

#define LD_KF(buf, chk) do {                                                   \
    const size_t m0_ = (size_t)(chk) * 64 + mh * 32;                           \
    buf[0] = *(const bf16x8*)(Kb + (m0_ +  0 + lo) * CQK + hi * 8);            \
    buf[1] = *(const bf16x8*)(Kb + (m0_ + 16 + lo) * CQK + hi * 8);            \
  } while (0)

#define SYNC_CHUNK() do {                                                      \
    __builtin_amdgcn_sched_barrier(0);                                         \
    asm volatile("s_waitcnt vmcnt(0)" ::: "memory");                           \
    __builtin_amdgcn_s_barrier();                                              \
    __builtin_amdgcn_sched_barrier(0);                                         \
  } while (0)

  auto produce = [&](const bf16x8* kf, bf16x8 qf) -> u32x4 {
    f32x4 s0 = mfma16(kf[0], qf, fz);
    f32x4 s1 = mfma16(kf[1], qf, fz);
#pragma unroll
    for (int r = 0; r < 4; r++) {
      s0[r] = __builtin_amdgcn_exp2f(s0[r]);
      s1[r] = __builtin_amdgcn_exp2f(s1[r]);
    }
    u32x4 o;
    o[0] = pkbf(s0[0], s0[1]); o[1] = pkbf(s0[2], s0[3]);
    o[2] = pkbf(s1[0], s1[1]); o[3] = pkbf(s1[2], s1[3]);
    return o;
  };

#define PV(pA, pB) do {                                                        \
    const bf16x8 aA = __builtin_bit_cast(bf16x8, pA);                          \
    const bf16x8 aB = __builtin_bit_cast(bf16x8, pB);                          \
    _Pragma("unroll")                                                          \
    for (int ct_ = 0; ct_ < 8; ct_++) {                                        \
      acc[0][ct_] = mfma16(aA, vf[ct_], acc[0][ct_]);                          \
      acc[1][ct_] = mfma16(aB, vf[ct_], acc[1][ct_]);                          \
    }                                                                          \
    acc_lA = mfma16(aA, ones, acc_lA);                                         \
    acc_lB = mfma16(aB, ones, acc_lB);                                         \
  } while (0)

  // Prologue: stage V(0); P(0) from K(0); K(1) into kfA.
  STAGE(0, 0);
  LD_KF(kfA, 0);
  pEA = produce(kfA, qfA);
  pEB = produce(kfA, qfB);
  LD_KF(kfA, 1);

  for (int ch = 0; ch < 64; ch += 2) {
    // EVEN body: read buf0 = V(ch); produce P(ch+1) from kfA = K(ch+1).
    if (ch + 1 < 64) { pOA = produce(kfA, qfA); pOB = produce(kfA, qfB); }
    SYNC_CHUNK();                       // drains stage(ch); V(ch) visible
    STAGE(1, ch + 1 < 64 ? ch + 1 : 63);
    LD_KF(kfB, ch + 2 < 64 ? ch + 2 : 63);
    RD_VF(0);
    PV(pEA, pEB);

    // ODD body: read buf1 = V(ch+1); produce P(ch+2) from kfB = K(ch+2).
    if (ch + 2 < 64) { pEA = produce(kfB, qfA); pEB = produce(kfB, qfB); }
    SYNC_CHUNK();                       // drains stage(ch+1)
    STAGE(0, ch + 2 < 64 ? ch + 2 : 63);
    LD_KF(kfA, ch + 3 < 64 ? ch + 3 : 63);
    RD_VF(1);
    PV(pOA, pOB);
  }
#undef STAGE
#undef RD_VF
#undef LD_KF
#undef SYNC_CHUNK
#undef PV

  // Protect Vs from epilogue-alias overwrite until all PV reads retired.
  __syncthreads();

  f32x4* Ox = (f32x4*)smem;              // [pair4][t2][ct8][lane64]
  f32x4* Lx = (f32x4*)(smem + 65536);    // [pair4][t2][lane64]
  const int pair = w >> 1;               // (qh, ch2) combo
  if (mh == 1) {
#pragma unroll
    for (int t = 0; t < 2; t++)
#pragma unroll
      for (int ct = 0; ct < 8; ct++)
        Ox[((pair * 2 + t) * 8 + ct) * 64 + lane] = acc[t][ct];
    Lx[(pair * 2 + 0) * 64 + lane] = acc_lA;
    Lx[(pair * 2 + 1) * 64 + lane] = acc_lB;
  }
  __syncthreads();
  if (mh == 0) {
    const float* xb = x   + (size_t)b * CCH * NTOK;
    float*       ob = out + (size_t)b * CCH * NTOK;
#pragma unroll
    for (int t = 0; t < 2; t++) {
      const int qbase = (t == 0) ? qA : qB;
      f32x4 lp = ((t == 0) ? acc_lA : acc_lB) + Lx[(pair * 2 + t) * 64 + lane];
      f32x4 il;
#pragma unroll
      for (int r = 0; r < 4; r++) il[r] = 1.f / lp[r];
#pragma unroll
      for (int ct = 0; ct < 8; ct++) {
        f32x4 tot = acc[t][ct] + Ox[((pair * 2 + t) * 8 + ct) * 64 + lane];
        int c = (ct0 + ct) * 16 + lo;
        size_t base = (size_t)c * NTOK + qbase + hi * 4;
        float4 xr = *(const float4*)(xb + base);
        float4 o;
        o.x = tot[0] * il[0] + xr.x;
        o.y = tot[1] * il[1] + xr.y;
        o.z = tot[2] * il[2] + xr.z;
        o.w = tot[3] * il[3] + xr.w;
        *(float4*)(ob + base) = o;
      }
    }
  }
}

extern "C" void kernel_launch(void* const* d_in, const int* in_sizes, int n_in,
                              void* d_out, int out_size, void* d_ws, size_t ws_size,
                              hipStream_t stream) {
  const float* x  = (const float*)d_in[0];
  const float* wq = (const float*)d_in[1];
  const float* bq = (const float*)d_in[2];
  const float* wk = (const float*)d_in[3];
  const float* bk = (const float*)d_in[4];
  const float* wv = (const float*)d_in[5];
  const float* bv = (const float*)d_in[6];
  float* out = (float*)d_out;

  // ws (bf16): Q [4,4096,32] | K [4,4096,32] | V tiled [4][64][16][2][512]
  // | Whi,Wlo [320,256]
  u16* Qp  = (u16*)d_ws;
  u16* Kp  = Qp + (size_t)NB * NTOK * CQK;
  u16* Vp  = Kp + (size_t)NB * NTOK * CQK;
  u16* Whi = Vp + (size_t)NB * CCH * NTOK;
  u16* Wlo = Whi + (size_t)320 * CCH;

  convert_w<<<80, 256, 0, stream>>>(wq, wk, wv, Whi, Wlo);
  dim3 pg(256, NB);
  qkv_proj<<<pg, 256, 0, stream>>>(x, bq, bk, bv, Whi, Wlo, Qp, Kp, Vp);
  attn<<<256, 512, 0, stream>>>(x, Qp, Kp, Vp, out);
}

// Round 15
// 95.376 us; speedup vs baseline: 1.3521x; 1.3521x over previous
//
#include <hip/hip_runtime.h>
#include <hip/hip_bf16.h>

#define NB   4
#define CCH  256
#define CQK  32
#define NTOK 4096
#define LOG2E 1.4426950408889634f

typedef unsigned short u16;
typedef unsigned int   u32;
typedef __attribute__((ext_vector_type(8))) __bf16 bf16x8;
typedef __attribute__((ext_vector_type(4))) float  f32x4;
typedef __attribute__((ext_vector_type(4))) u32    u32x4;

union bfu { bf16x8 v; u16 s[8]; u32 w[4]; };

static __device__ __forceinline__ u16 f2bf(float f) {
  union { __hip_bfloat16 h; u16 u; } c; c.h = __float2bfloat16(f); return c.u;
}
static __device__ __forceinline__ float bf2f(u16 u) {
  union { __hip_bfloat16 h; u16 u; } c; c.u = u; return __bfloat162float(c.h);
}
// Safe packed f32->bf16 pair (round-half-up, ~ulp of RNE). Plain integer ops
// (R11's v_cvt_pk_bf16_f32 asm was the correctness poison — do not reuse).
static __device__ __forceinline__ u32 pkbf(float a, float b) {
  u32 ua = __builtin_bit_cast(u32, a) + 0x8000u;
  u32 ub = __builtin_bit_cast(u32, b) + 0x8000u;
  return (ua >> 16) | (ub & 0xFFFF0000u);
}
static __device__ __forceinline__ f32x4 mfma16(bf16x8 a, bf16x8 b, f32x4 c) {
  return __builtin_amdgcn_mfma_f32_16x16x32_bf16(a, b, c, 0, 0, 0);
}

// V tiled layout (since R9): per (b, ch=m/64) a contiguous 32KB slab
// [ct 16][mh 2][512 u16]; u16 slot (hi*16+lo)*8+j =
// V[m=ch*64+mh*32+16*(j>>2)+4hi+(j&3)][c=ct*16+lo].

// ---------------- Kernel 0: split W to bf16 hi/lo (once, tiny) ----------------
__global__ __launch_bounds__(256) void convert_w(
    const float* __restrict__ wq, const float* __restrict__ wk,
    const float* __restrict__ wv, u16* __restrict__ whi, u16* __restrict__ wlo)
{
  int i   = blockIdx.x * 256 + threadIdx.x;  // float4 index, 320*64 total
  int row = i >> 6;
  int col = (i & 63) * 4;
  const float* src = (row < 32) ? wq + row * CCH
                   : (row < 64) ? wk + (row - 32) * CCH
                                : wv + (row - 64) * CCH;
  float sc = (row < 32) ? LOG2E : 1.0f;
  float4 v = *(const float4*)(src + col);
  float f[4] = { v.x * sc, v.y * sc, v.z * sc, v.w * sc };
  u16 h[4], l[4];
#pragma unroll
  for (int j = 0; j < 4; j++) {
    h[j] = f2bf(f[j]);
    l[j] = f2bf(f[j] - bf2f(h[j]));
  }
  uint2 ph = { (u32)h[0] | ((u32)h[1] << 16), (u32)h[2] | ((u32)h[3] << 16) };
  uint2 pl = { (u32)l[0] | ((u32)l[1] << 16), (u32)l[2] | ((u32)l[3] << 16) };
  *(uint2*)(whi + (size_t)i * 4) = ph;
  *(uint2*)(wlo + (size_t)i * 4) = pl;
}

// ---------------- Kernel 1: MFMA QKV projection (R13 version: n-tile 32) -----
__attribute__((amdgpu_waves_per_eu(2, 4)))
__global__ __launch_bounds__(256) void qkv_proj(
    const float* __restrict__ x,
    const float* __restrict__ bq, const float* __restrict__ bk,
    const float* __restrict__ bv,
    const u16* __restrict__ whi, const u16* __restrict__ wlo,
    u16* __restrict__ Qo, u16* __restrict__ Ko, u16* __restrict__ Vo)
{
  const int nt = blockIdx.x;
  const int b  = blockIdx.y;
  const int n0 = nt * 32;
  const int tid = threadIdx.x;
  const int w = tid >> 6, lane = tid & 63, lo = lane & 15, hi = lane >> 4;

  const f32x4 fz = { 0.f, 0.f, 0.f, 0.f };
  f32x4 acc[5][2];
#pragma unroll
  for (int t = 0; t < 5; t++) { acc[t][0] = fz; acc[t][1] = fz; }

  const float* xb = x + (size_t)b * CCH * NTOK;

  for (int k = 0; k < 8; k++) {
    const int ck = k * 32;
    bf16x8 xh[2], xl[2];
#pragma unroll
    for (int nt2 = 0; nt2 < 2; nt2++) {
      const float* xc = xb + (size_t)(ck + hi * 8) * NTOK + n0 + nt2 * 16 + lo;
      u32  bw[8];
      float rl[8];
#pragma unroll
      for (int j = 0; j < 8; j++) {
        float f  = xc[(size_t)j * NTOK];
        u32 bits = __builtin_bit_cast(u32, f);
        float fh = __builtin_bit_cast(float, bits & 0xFFFF0000u);
        bw[j] = bits;
        rl[j] = f - fh;
      }
      bfu H, L;
#pragma unroll
      for (int j = 0; j < 4; j++) {
        H.w[j] = (bw[2 * j] >> 16) | (bw[2 * j + 1] & 0xFFFF0000u);
        L.w[j] = pkbf(rl[2 * j], rl[2 * j + 1]);
      }
      xh[nt2] = H.v; xl[nt2] = L.v;
    }
#pragma unroll
    for (int t = 0; t < 5; t++) {
      const int ot = w + t * 4;
      const size_t woff = (size_t)(ot * 16 + lo) * CCH + ck + hi * 8;
      bf16x8 wh = *(const bf16x8*)(whi + woff);
      bf16x8 wl = *(const bf16x8*)(wlo + woff);
#pragma unroll
      for (int nt2 = 0; nt2 < 2; nt2++) {
        if (t == 0) {   // Q/K: D[row=o][col=n]
          acc[t][nt2] = mfma16(wh, xh[nt2], acc[t][nt2]);
          acc[t][nt2] = mfma16(wh, xl[nt2], acc[t][nt2]);
          acc[t][nt2] = mfma16(wl, xh[nt2], acc[t][nt2]);
        } else {        // V: D[row=n][col=c]
          acc[t][nt2] = mfma16(xh[nt2], wh, acc[t][nt2]);
          acc[t][nt2] = mfma16(xl[nt2], wh, acc[t][nt2]);
          acc[t][nt2] = mfma16(xh[nt2], wl, acc[t][nt2]);
        }
      }
    }
  }

  {
    const float* bsrc = (w < 2) ? bq : bk;
    const float  sc   = (w < 2) ? LOG2E : 1.0f;
    float4 b4 = *(const float4*)(bsrc + (w & 1) * 16 + hi * 4);
    float b0 = b4.x * sc, b1 = b4.y * sc, b2 = b4.z * sc, b3 = b4.w * sc;
    u16* base = (w < 2) ? Qo : Ko;
#pragma unroll
    for (int nt2 = 0; nt2 < 2; nt2++) {
      int n = n0 + nt2 * 16 + lo;
      f32x4 a = acc[0][nt2];
      uint2 pk = { pkbf(a[0] + b0, a[1] + b1), pkbf(a[2] + b2, a[3] + b3) };
      *(uint2*)(base + ((size_t)b * NTOK + n) * CQK + (w & 1) * 16 + hi * 4) = pk;
    }
  }
  // V epilogue -> tiled layout.
  {
    const int chk = n0 >> 6;
    const int mh  = (n0 >> 5) & 1;
    u16* vtb = Vo + ((size_t)b * 64 + chk) * 16384 + mh * 512 + (hi * 16 + lo) * 8;
#pragma unroll
    for (int t = 1; t < 5; t++) {
      int ct = w + t * 4 - 4;
      float bvc = bv[ct * 16 + lo];
#pragma unroll
      for (int nt2 = 0; nt2 < 2; nt2++) {
        f32x4 a = acc[t][nt2];
        uint2 pk = { pkbf(a[0] + bvc, a[1] + bvc), pkbf(a[2] + bvc, a[3] + bvc) };
        *(uint2*)(vtb + (size_t)ct * 1024 + nt2 * 4) = pk;
      }
    }
  }
}

// ---------------- Kernel 2: flash attention, q-complete waves (V dup=1) ------
// Grid 256 x 512 thr, main loop barrier-free. Wave = (ch2 = c-128-half,
// mq = 32-m quarter of a 128-m block) and processes ALL 64 queries ->
// every V fragment read by exactly ONE wave (L1 V traffic halves vs R13).
// acc[4 qt][8 ct] = 128 VGPR; V/K reg-double-buffered; P pair-wise.
// O/l combined across mq partners in a 4-phase LDS epilogue.
__attribute__((amdgpu_waves_per_eu(2, 2)))
__global__ __launch_bounds__(512) void attn(
    const float* __restrict__ x,
    const u16* __restrict__ Qm, const u16* __restrict__ Km,
    const u16* __restrict__ Vm, float* __restrict__ out)
{
  const int g   = blockIdx.x;
  const int lw3 = g & 7;
  const int b   = lw3 >> 1;                      // batch -> XCD pair
  const int qt6 = ((g >> 3) << 1) | (lw3 & 1);
  const int q0  = qt6 * 64;

  const int tid  = threadIdx.x;
  const int w    = tid >> 6;
  const int lane = tid & 63;
  const int lo   = lane & 15;
  const int hi   = lane >> 4;
  const int ch2  = w >> 2;               // 0/1: c 128-half
  const int mq   = w & 3;                // 0..3: 32-m quarter of 128-m block
  const int ct0  = ch2 * 8;

  __shared__ __align__(16) f32x4 Ox[2][3][8][64];   // 48KB epilogue exchange
  __shared__ float l_scr[4][64];                    // [mq][q]

  const f32x4 fz = { 0.f, 0.f, 0.f, 0.f };
  const u16* Kb = Km + (size_t)b * NTOK * CQK;
  // Wave's V slice: slab = 2t + (mq>>1), half (mq&1), c-tiles ct0..ct0+7.
  const u16* Vb = Vm + (size_t)b * 64 * 16384 + (mq >> 1) * 16384
                + (size_t)ct0 * 1024 + (mq & 1) * 512 + lane * 8;

  bf16x8 qf[4];
#pragma unroll
  for (int qt = 0; qt < 4; qt++)
    qf[qt] = *(const bf16x8*)(Qm + ((size_t)b * NTOK + q0 + qt * 16 + lo) * CQK + hi * 8);

  f32x4 acc[4][8];
#pragma unroll
  for (int qt = 0; qt < 4; qt++)
#pragma unroll
    for (int ct = 0; ct < 8; ct++) acc[qt][ct] = fz;
  float ls0 = 0.f, ls1 = 0.f, ls2 = 0.f, ls3 = 0.f;

  bf16x8 vfA[8], vfB[8], kfA[2], kfB[2];
  u32x4 p0, p1;

#define LD_VF(buf, t) do {                                                     \
    const u16* vc_ = Vb + (size_t)(t) * 32768;                                 \
    _Pragma("unroll")                                                          \
    for (int ct_ = 0; ct_ < 8; ct_++)                                          \
      buf[ct_] = *(const bf16x8*)(vc_ + ct_ * 1024);                           \
  } while (0)

#define LD_KF(buf, t) do {                                                     \
    const size_t m0_ = (size_t)(t) * 128 + mq * 32;                            \
    buf[0] = *(const bf16x8*)(Kb + (m0_ +  0 + lo) * CQK + hi * 8);            \
    buf[1] = *(const bf16x8*)(Kb + (m0_ + 16 + lo) * CQK + hi * 8);            \
  } while (0)

  // QK^T + exp2 + pack for q-tiles (qa,qb) over this wave's 32-m slice.
  // p element j <-> m_rel = 16*(j>>2) + 4hi + (j&3) (tiled-V slot order).
  auto prod2 = [&](const bf16x8* kf, bf16x8 qa, bf16x8 qb,
                   float& la, float& lb, u32x4& pa, u32x4& pb) {
    f32x4 a0 = mfma16(kf[0], qa, fz);
    f32x4 a1 = mfma16(kf[1], qa, fz);
    f32x4 b0 = mfma16(kf[0], qb, fz);
    f32x4 b1 = mfma16(kf[1], qb, fz);
#pragma unroll
    for (int r = 0; r < 4; r++) {
      a0[r] = __builtin_amdgcn_exp2f(a0[r]);
      a1[r] = __builtin_amdgcn_exp2f(a1[r]);
      b0[r] = __builtin_amdgcn_exp2f(b0[r]);
      b1[r] = __builtin_amdgcn_exp2f(b1[r]);
    }
    la += ((a0[0] + a0[1]) + (a0[2] + a0[3])) + ((a1[0] + a1[1]) + (a1[2] + a1[3]));
    lb += ((b0[0] + b0[1]) + (b0[2] + b0[3])) + ((b1[0] + b1[1]) + (b1[2] + b1[3]));
    pa[0] = pkbf(a0[0], a0[1]); pa[1] = pkbf(a0[2], a0[3]);
    pa[2] = pkbf(a1[0], a1[1]); pa[3] = pkbf(a1[2], a1[3]);
    pb[0] = pkbf(b0[0], b0[1]); pb[1] = pkbf(b0[2], b0[3]);
    pb[2] = pkbf(b1[0], b1[1]); pb[3] = pkbf(b1[2], b1[3]);
  };

#define PV2(pa, pb, qa, qb, vbuf) do {                                         \
    const bf16x8 aA = __builtin_bit_cast(bf16x8, pa);                          \
    const bf16x8 aB = __builtin_bit_cast(bf16x8, pb);                          \
    _Pragma("unroll")                                                          \
    for (int ct_ = 0; ct_ < 8; ct_++) {                                        \
      acc[qa][ct_] = mfma16(aA, vbuf[ct_], acc[qa][ct_]);                      \
      acc[qb][ct_] = mfma16(aB, vbuf[ct_], acc[qb][ct_]);                      \
    }                                                                          \
  } while (0)

  // Prologue: V(0), K(0) in flight.
  LD_VF(vfA, 0);
  LD_KF(kfA, 0);

  for (int t = 0; t < 32; t += 2) {
    // EVEN body: consume vfA/kfA = block t.
    if (t + 1 < 32) { LD_VF(vfB, t + 1); LD_KF(kfB, t + 1); }
    prod2(kfA, qf[0], qf[1], ls0, ls1, p0, p1);
    PV2(p0, p1, 0, 1, vfA);
    prod2(kfA, qf[2], qf[3], ls2, ls3, p0, p1);
    PV2(p0, p1, 2, 3, vfA);

    // ODD body: consume vfB/kfB = block t+1.
    if (t + 1 < 32) {
      if (t + 2 < 32) { LD_VF(vfA, t + 2); LD_KF(kfA, t + 2); }
      prod2(kfB, qf[0], qf[1], ls0, ls1, p0, p1);
      PV2(p0, p1, 0, 1, vfB);
      prod2(kfB, qf[2], qf[3], ls2, ls3, p0, p1);
      PV2(p0, p1, 2, 3, vfB);
    }
  }
#undef LD_VF
#undef LD_KF
#undef PV2

  // l partials: lane holds sum over its 8 m's for q=lo; reduce over hi lanes.
  ls0 += __shfl_xor(ls0, 16); ls0 += __shfl_xor(ls0, 32);
  ls1 += __shfl_xor(ls1, 16); ls1 += __shfl_xor(ls1, 32);
  ls2 += __shfl_xor(ls2, 16); ls2 += __shfl_xor(ls2, 32);
  ls3 += __shfl_xor(ls3, 16); ls3 += __shfl_xor(ls3, 32);
  // produce is duplicated across ch2 -> ch2==0 copies suffice.
  if (ch2 == 0 && hi == 0) {
    l_scr[mq][ 0 + lo] = ls0;
    l_scr[mq][16 + lo] = ls1;
    l_scr[mq][32 + lo] = ls2;
    l_scr[mq][48 + lo] = ls3;
  }

  // 4-phase epilogue: combine O across the 4 mq partners of each ch2.
  const float* xb = x   + (size_t)b * CCH * NTOK;
  float*       ob = out + (size_t)b * CCH * NTOK;
#pragma unroll
  for (int qt = 0; qt < 4; ++qt) {
    if (mq != 0) {
#pragma unroll
      for (int ct = 0; ct < 8; ct++) Ox[ch2][mq - 1][ct][lane] = acc[qt][ct];
    }
    __syncthreads();
    if (mq == 0) {
      f32x4 lp = *(const f32x4*)&l_scr[0][qt * 16 + hi * 4];
      lp += *(const f32x4*)&l_scr[1][qt * 16 + hi * 4];
      lp += *(const f32x4*)&l_scr[2][qt * 16 + hi * 4];
      lp += *(const f32x4*)&l_scr[3][qt * 16 + hi * 4];
      f32x4 il;
#pragma unroll
      for (int r = 0; r < 4; r++) il[r] = 1.f / lp[r];
#pragma unroll
      for (int ct = 0; ct < 8; ct++) {
        f32x4 tot = acc[qt][ct] + Ox[ch2][0][ct][lane]
                  + Ox[ch2][1][ct][lane] + Ox[ch2][2][ct][lane];
        int c = ch2 * 128 + ct * 16 + lo;
        size_t base = (size_t)c * NTOK + q0 + qt * 16 + hi * 4;
        float4 xr = *(const float4*)(xb + base);
        float4 o;
        o.x = tot[0] * il[0] + xr.x;
        o.y = tot[1] * il[1] + xr.y;
        o.z = tot[2] * il[2] + xr.z;
        o.w = tot[3] * il[3] + xr.w;
        *(float4*)(ob + base) = o;
      }
    }
    __syncthreads();
  }
}

extern "C" void kernel_launch(void* const* d_in, const int* in_sizes, int n_in,
                              void* d_out, int out_size, void* d_ws, size_t ws_size,
                              hipStream_t stream) {
  const float* x  = (const float*)d_in[0];
  const float* wq = (const float*)d_in[1];
  const float* bq = (const float*)d_in[2];
  const float* wk = (const float*)d_in[3];
  const float* bk = (const float*)d_in[4];
  const float* wv = (const float*)d_in[5];
  const float* bv = (const float*)d_in[6];
  float* out = (float*)d_out;

  // ws (bf16): Q [4,4096,32] | K [4,4096,32] | V tiled [4][64][16][2][512]
  // | Whi,Wlo [320,256]
  u16* Qp  = (u16*)d_ws;
  u16* Kp  = Qp + (size_t)NB * NTOK * CQK;
  u16* Vp  = Kp + (size_t)NB * NTOK * CQK;
  u16* Whi = Vp + (size_t)NB * CCH * NTOK;
  u16* Wlo = Whi + (size_t)320 * CCH;

  convert_w<<<80, 256, 0, stream>>>(wq, wk, wv, Whi, Wlo);
  dim3 pg(128, NB);
  qkv_proj<<<pg, 256, 0, stream>>>(x, bq, bk, bv, Whi, Wlo, Qp, Kp, Vp);
  attn<<<256, 512, 0, stream>>>(x, Qp, Kp, Vp, out);
}